// Round 15
// baseline (459.831 us; speedup 1.0000x reference)
//
#include <hip/hip_runtime.h>
#include <hip/hip_fp16.h>

#define NN 100000     // num nodes
#define NE 1600000    // num edges
#define NEL 200000    // link-pred edges
#define TM 64         // nodes per block in k_hw1
#define TM2 128       // nodes per block in k_hw2

// Bucketed CSR build (R12 config): bucket = dst >> 9 (512 dsts per bucket).
#define NBUCK 196     // ceil(NN/512)
#define CAPB  10240   // per-bucket capacity (mean 8163, sigma ~90)
#define TPE   8192    // edges per k_part block (196 blocks)

// ---------------- CSR build, pass A: partition edges into buckets ----------
__global__ __launch_bounds__(256) void k_part(const int* __restrict__ src,
                                              const int* __restrict__ dst,
                                              int* __restrict__ gcur,
                                              int* __restrict__ part) {
    __shared__ int hist[NBUCK];
    __shared__ int base[NBUCK];
    __shared__ int rk[NBUCK];
    int tid = threadIdx.x;
    for (int i = tid; i < NBUCK; i += 256) { hist[i] = 0; rk[i] = 0; }
    __syncthreads();
    int e0 = blockIdx.x * TPE;
    int e1 = min(e0 + TPE, NE);
    for (int e = e0 + tid; e < e1; e += 256)
        atomicAdd(&hist[dst[e] >> 9], 1);
    __syncthreads();
    for (int i = tid; i < NBUCK; i += 256)
        base[i] = i * CAPB + atomicAdd(&gcur[i], hist[i]);
    __syncthreads();
    for (int e = e0 + tid; e < e1; e += 256) {
        int d = dst[e];
        int s = src[e];
        int b = d >> 9;
        int r = atomicAdd(&rk[b], 1);
        part[base[b] + r] = ((d & 511) << 17) | s;   // src < 2^17
    }
}

// ---------------- CSR build, pass B: per-bucket LDS sort (prefix fused) ----
__global__ __launch_bounds__(256) void k_build(const int* __restrict__ gcur,
                                               const int* __restrict__ part,
                                               int* __restrict__ csr,
                                               int* __restrict__ off,
                                               float* __restrict__ dinv) {
    __shared__ int cnts[256];
    __shared__ int hist[512];
    __shared__ int loff[512];
    __shared__ int ssum[256];
    __shared__ int csrbuf[CAPB];
    int b = blockIdx.x;
    int tid = threadIdx.x;
    cnts[tid] = (tid < NBUCK) ? gcur[tid] : 0;       // inline bucket prefix
    __syncthreads();
    for (int st = 1; st < 256; st <<= 1) {
        int tmp = (tid >= st) ? cnts[tid - st] : 0;
        __syncthreads();
        cnts[tid] += tmp;
        __syncthreads();
    }
    int obase = (b == 0) ? 0 : cnts[b - 1];
    int cnt = gcur[b];
    int pbase = b * CAPB;
    hist[tid] = 0; hist[tid + 256] = 0;
    __syncthreads();
    for (int i = tid; i < cnt; i += 256)
        atomicAdd(&hist[part[pbase + i] >> 17], 1);
    __syncthreads();
    int a0 = hist[2 * tid], a1 = hist[2 * tid + 1];
    int pairs = a0 + a1;
    ssum[tid] = pairs;
    __syncthreads();
    for (int st = 1; st < 256; st <<= 1) {
        int tmp = (tid >= st) ? ssum[tid - st] : 0;
        __syncthreads();
        ssum[tid] += tmp;
        __syncthreads();
    }
    int pexcl = ssum[tid] - pairs;
    loff[2 * tid] = pexcl;
    loff[2 * tid + 1] = pexcl + a0;
    __syncthreads();
    for (int i = tid; i < 512; i += 256) {
        int d = b * 512 + i;
        if (d < NN) {
            int c = hist[i];
            off[d] = obase + loff[i] + c;            // end of row d
            dinv[d] = rsqrtf((float)(c + 1));        // +1 self-loop
        }
    }
    hist[tid] = 0; hist[tid + 256] = 0;              // reuse as rank counters
    __syncthreads();
    for (int i = tid; i < cnt; i += 256) {
        int rec = part[pbase + i];
        int dl = rec >> 17;
        int r = atomicAdd(&hist[dl], 1);
        csrbuf[loff[dl] + r] = rec & 0x1FFFF;
    }
    __syncthreads();
    for (int i = tid; i < cnt; i += 256)             // coalesced flush
        csr[obase + i] = csrbuf[i];
}

// ---------------- hw1' = dinv * ([x|pos] @ W1)  (80 -> 64), fp16 out -------
__global__ __launch_bounds__(256) void k_hw1(const float* __restrict__ x,
                                             const float* __restrict__ pos,
                                             const float* __restrict__ W1,
                                             const float* __restrict__ dinv,
                                             __half* __restrict__ hw1) {
    __shared__ float sh[TM * 80];
    __shared__ float sw[80 * 64];
    int tid = threadIdx.x;
    for (int t = tid; t < 80 * 64; t += 256) sw[t] = W1[t];
    int nb = blockIdx.x * TM;
    for (int i = tid; i < TM * 64; i += 256) {
        int node = i >> 6, ch = i & 63;
        int g = nb + node;
        sh[node * 80 + ch] = (g < NN) ? x[g * 64 + ch] : 0.0f;
    }
    for (int i = tid; i < TM * 16; i += 256) {
        int node = i >> 4, ch = i & 15;
        int g = nb + node;
        sh[node * 80 + 64 + ch] = (g < NN) ? pos[g * 16 + ch] : 0.0f;
    }
    __syncthreads();
    int j  = (tid & 15) * 4;
    int nl = (tid >> 4) * 4;
    float a00=0,a01=0,a02=0,a03=0, a10=0,a11=0,a12=0,a13=0;
    float a20=0,a21=0,a22=0,a23=0, a30=0,a31=0,a32=0,a33=0;
#pragma unroll 4
    for (int k = 0; k < 80; ++k) {
        float4 wv = *(const float4*)&sw[k * 64 + j];
        float h0 = sh[(nl + 0) * 80 + k];
        float h1 = sh[(nl + 1) * 80 + k];
        float h2 = sh[(nl + 2) * 80 + k];
        float h3 = sh[(nl + 3) * 80 + k];
        a00 += h0 * wv.x; a01 += h0 * wv.y; a02 += h0 * wv.z; a03 += h0 * wv.w;
        a10 += h1 * wv.x; a11 += h1 * wv.y; a12 += h1 * wv.z; a13 += h1 * wv.w;
        a20 += h2 * wv.x; a21 += h2 * wv.y; a22 += h2 * wv.z; a23 += h2 * wv.w;
        a30 += h3 * wv.x; a31 += h3 * wv.y; a32 += h3 * wv.z; a33 += h3 * wv.w;
    }
    int g0 = nb + nl;
    union { __half2 h2v[2]; float2 f2; } u;
#define STORE_ROW(r, b0, b1, b2, b3)                                          \
    if (g0 + r < NN) {                                                        \
        float sc = dinv[g0 + r];                                              \
        u.h2v[0] = __floats2half2_rn(b0 * sc, b1 * sc);                       \
        u.h2v[1] = __floats2half2_rn(b2 * sc, b3 * sc);                       \
        *(float2*)&hw1[(g0 + r) * 64 + j] = u.f2;                             \
    }
    STORE_ROW(0, a00, a01, a02, a03)
    STORE_ROW(1, a10, a11, a12, a13)
    STORE_ROW(2, a20, a21, a22, a23)
    STORE_ROW(3, a30, a31, a32, a33)
#undef STORE_ROW
}

// ---------------- layer-1 gather, XCD channel-sliced (4 quarters) ----------
// h2[d][c] = relu(b1[c] + dinv[d] * (sum_e hw1'[s] + hw1'[d]))
// Quarter q = (blockIdx&7)>>1: blocks on XCDs {2q,2q+1} (round-robin
// heuristic) touch only hw1 channel bytes [q*32, q*32+32) -> per-XCD
// footprint 3.2 MB, fits the 4 MB L2 (R14: whole-table gather = 102 MB
// compulsory + 50 MB capacity FETCH). Wave = 4 edges x 16 channels; per-edge
// wave-load count unchanged. Edge loop shuffle-free; the 2 xor-reduces run
// at full reconvergence; divergent tail has no cross-lane ops (R3 rule).
__global__ __launch_bounds__(256) void k_gather1(const int* __restrict__ off,
                                                 const int* __restrict__ csr,
                                                 const float* __restrict__ dinv,
                                                 const __half* __restrict__ hw,
                                                 const float* __restrict__ b1,
                                                 __half* __restrict__ h2out) {
    int g  = blockIdx.x & 7;
    int q  = g >> 1;                            // channel quarter 0..3
    int rb = (blockIdx.x >> 3) * 2 + (g & 1);   // row-block 0..24999
    int wave = threadIdx.x >> 6;
    int lane = threadIdx.x & 63;
    int d = rb * 4 + wave;
    int eg = lane >> 4;                         // edge sub-group 0..3
    int ch = q * 16 + (lane & 15);              // absolute channel
    int start = (d == 0) ? 0 : off[d - 1];
    int end = off[d];
    start = __builtin_amdgcn_readfirstlane(start);
    end   = __builtin_amdgcn_readfirstlane(end);
    float dd = dinv[d];
    float hself = __half2float(hw[d * 64 + ch]);     // hoisted
    float acc0 = 0.0f, acc1 = 0.0f;
    int e = start;
    for (; e + 7 < end; e += 8) {               // 8 edges/iter, 2 loads deep
        int sA = csr[e + eg];                   // broadcast within 16 lanes
        int sB = csr[e + 4 + eg];
        acc0 += __half2float(hw[sA * 64 + ch]);
        acc1 += __half2float(hw[sB * 64 + ch]);
    }
    for (int ee = e + eg; ee < end; ee += 4)    // divergent-safe tail
        acc0 += __half2float(hw[csr[ee] * 64 + ch]);
    float acc = acc0 + acc1;
    acc += __shfl_xor(acc, 16, 64);             // combine 4 edge sub-groups
    acc += __shfl_xor(acc, 32, 64);             // (full exec)
    if (lane < 16) {
        float v = fmaxf(b1[ch] + dd * (acc + hself), 0.0f);
        h2out[d * 64 + ch] = __float2half_rn(v);
    }
}

// ---------------- hw2' = dinv * (h2 @ W2)  (64 -> 32), fp16 in/out ---------
__global__ __launch_bounds__(256) void k_hw2(const __half* __restrict__ h2,
                                             const float* __restrict__ W2,
                                             const float* __restrict__ dinv,
                                             __half* __restrict__ hw2) {
    __shared__ float sh[TM2 * 65];  // [node][feat], stride 65 (pad)
    __shared__ float sw[64 * 32];
    int tid = threadIdx.x;
    for (int t = tid; t < 64 * 32; t += 256) sw[t] = W2[t];
    int nb = blockIdx.x * TM2;
    for (int i = tid; i < TM2 * 64; i += 256) {
        int node = i >> 6, ch = i & 63;
        int g = nb + node;
        sh[node * 65 + ch] = (g < NN) ? __half2float(h2[g * 64 + ch]) : 0.0f;
    }
    __syncthreads();
    int j  = (tid & 7) * 4;
    int nl = (tid >> 3) * 4;
    float a00=0,a01=0,a02=0,a03=0, a10=0,a11=0,a12=0,a13=0;
    float a20=0,a21=0,a22=0,a23=0, a30=0,a31=0,a32=0,a33=0;
#pragma unroll 4
    for (int k = 0; k < 64; ++k) {
        float4 wv = *(const float4*)&sw[k * 32 + j];
        float h0 = sh[(nl + 0) * 65 + k];
        float h1 = sh[(nl + 1) * 65 + k];
        float h2v = sh[(nl + 2) * 65 + k];
        float h3 = sh[(nl + 3) * 65 + k];
        a00 += h0 * wv.x;  a01 += h0 * wv.y;  a02 += h0 * wv.z;  a03 += h0 * wv.w;
        a10 += h1 * wv.x;  a11 += h1 * wv.y;  a12 += h1 * wv.z;  a13 += h1 * wv.w;
        a20 += h2v * wv.x; a21 += h2v * wv.y; a22 += h2v * wv.z; a23 += h2v * wv.w;
        a30 += h3 * wv.x;  a31 += h3 * wv.y;  a32 += h3 * wv.z;  a33 += h3 * wv.w;
    }
    int g0 = nb + nl;
    union { __half2 h2v2[2]; float2 f2; } u;
#define STORE_ROW(r, b0, b1, b2, b3)                                          \
    if (g0 + r < NN) {                                                        \
        float sc = dinv[g0 + r];                                              \
        u.h2v2[0] = __floats2half2_rn(b0 * sc, b1 * sc);                      \
        u.h2v2[1] = __floats2half2_rn(b2 * sc, b3 * sc);                      \
        *(float2*)&hw2[(g0 + r) * 32 + j] = u.f2;                             \
    }
    STORE_ROW(0, a00, a01, a02, a03)
    STORE_ROW(1, a10, a11, a12, a13)
    STORE_ROW(2, a20, a21, a22, a23)
    STORE_ROW(3, a30, a31, a32, a33)
#undef STORE_ROW
}

// ---------------- layer-2 gather, XCD channel-sliced (2 halves) ------------
// z[d][j] = b2[j] + dinv[d] * (sum_e hw2'[s] + hw2'[d])
// Half h = (blockIdx&7)>>2 -> XCDs 0-3 / 4-7 each touch 3.2 MB of hw2'.
__global__ __launch_bounds__(256) void k_gather2(const int* __restrict__ off,
                                                 const int* __restrict__ csr,
                                                 const float* __restrict__ dinv,
                                                 const __half* __restrict__ hw,
                                                 const float* __restrict__ b2,
                                                 float* __restrict__ outz) {
    int g  = blockIdx.x & 7;
    int h  = g >> 2;                            // channel half 0..1
    int rb = (blockIdx.x >> 3) * 4 + (g & 3);   // row-block 0..24999
    int wave = threadIdx.x >> 6;
    int lane = threadIdx.x & 63;
    int d = rb * 4 + wave;
    int eg = lane >> 4;                         // edge sub-group 0..3
    int ch = h * 16 + (lane & 15);              // absolute channel (of 32)
    int start = (d == 0) ? 0 : off[d - 1];
    int end = off[d];
    start = __builtin_amdgcn_readfirstlane(start);
    end   = __builtin_amdgcn_readfirstlane(end);
    float dd = dinv[d];
    float hself = __half2float(hw[d * 32 + ch]);     // hoisted
    float acc0 = 0.0f, acc1 = 0.0f;
    int e = start;
    for (; e + 7 < end; e += 8) {
        int sA = csr[e + eg];
        int sB = csr[e + 4 + eg];
        acc0 += __half2float(hw[sA * 32 + ch]);
        acc1 += __half2float(hw[sB * 32 + ch]);
    }
    for (int ee = e + eg; ee < end; ee += 4)    // divergent-safe tail
        acc0 += __half2float(hw[csr[ee] * 32 + ch]);
    float acc = acc0 + acc1;
    acc += __shfl_xor(acc, 16, 64);             // combine edge sub-groups
    acc += __shfl_xor(acc, 32, 64);             // (full exec)
    if (lane < 16)
        outz[d * 32 + ch] = b2[ch] + dd * (acc + hself);
}

// ---------------- link prediction head: 16 lanes per edge ------------------
__global__ __launch_bounds__(256) void k_linkpred(const int* __restrict__ sidx,
                                                  const int* __restrict__ didx,
                                                  const float* __restrict__ z,
                                                  const float* __restrict__ Wl,
                                                  const float* __restrict__ bl,
                                                  float* __restrict__ pred) {
    int t = blockIdx.x * blockDim.x + threadIdx.x;
    int e = t >> 4;
    int l = t & 15;
    int s = sidx[e], d = didx[e];
    float2 zs = *(const float2*)&z[s * 32 + 2 * l];
    float2 zd = *(const float2*)&z[d * 32 + 2 * l];
    float2 ws = *(const float2*)&Wl[2 * l];
    float2 wd = *(const float2*)&Wl[32 + 2 * l];
    float v = zs.x * ws.x + zs.y * ws.y + zd.x * wd.x + zd.y * wd.y;
    v += __shfl_xor(v, 1, 64);
    v += __shfl_xor(v, 2, 64);
    v += __shfl_xor(v, 4, 64);
    v += __shfl_xor(v, 8, 64);
    if (l == 0) pred[e] = v + bl[0];
}

extern "C" void kernel_launch(void* const* d_in, const int* in_sizes, int n_in,
                              void* d_out, int out_size, void* d_ws, size_t ws_size,
                              hipStream_t stream) {
    const float* x    = (const float*)d_in[0];
    const float* pos  = (const float*)d_in[1];
    const float* W1   = (const float*)d_in[2];
    const float* b1   = (const float*)d_in[3];
    const float* W2   = (const float*)d_in[4];
    const float* b2   = (const float*)d_in[5];
    const float* Wl   = (const float*)d_in[6];
    const float* bl   = (const float*)d_in[7];
    const int*   ei   = (const int*)d_in[8];   // [2, NE]
    const int*   eli  = (const int*)d_in[9];   // [2, NEL]
    const int* src  = ei;
    const int* dst  = ei + NE;
    const int* lsrc = eli;
    const int* ldst = eli + NEL;

    float* out_z    = (float*)d_out;            // [NN, 32]
    float* out_pred = (float*)d_out + NN * 32;  // [NEL]

    // workspace: dinv[NN]f | off[NN]i | gcur[NBUCK] | csr[NE]i |
    //            hw1'[NN*64]h (aliases part[NBUCK*CAPB]i = 8.0 MB, dead after
    //            k_build) | h2[NN*64]h | hw2'[NN*32]h   ~= 39.2 MB
    float*  dinv  = (float*)d_ws;
    int*    off   = (int*)(dinv + NN);
    int*    gcur  = off + NN;
    int*    csr   = gcur + NBUCK;
    __half* hw1   = (__half*)(csr + NE);
    int*    part  = (int*)hw1;                  // 8.0 MB <= hw1's 12.8 MB
    __half* h2    = hw1 + NN * 64;
    __half* hw2   = h2 + NN * 64;

    // 1) CSR build: partition -> per-bucket LDS sort (prefix fused, +dinv)
    hipMemsetAsync(gcur, 0, NBUCK * sizeof(int), stream);
    k_part<<<(NE + TPE - 1) / TPE, 256, 0, stream>>>(src, dst, gcur, part);
    k_build<<<NBUCK, 256, 0, stream>>>(gcur, part, csr, off, dinv);

    // 2) hw1' = dinv * ([x|pos] @ W1), fp16  (overwrites part — now dead)
    k_hw1<<<(NN + TM - 1) / TM, 256, 0, stream>>>(x, pos, W1, dinv, hw1);

    // 3) layer-1 gather + bias + relu -> h2 (fp16), XCD channel-sliced x4
    k_gather1<<<NN, 256, 0, stream>>>(off, csr, dinv, hw1, b1, h2);

    // 4) hw2' = dinv * (h2 @ W2), fp16
    k_hw2<<<(NN + TM2 - 1) / TM2, 256, 0, stream>>>(h2, W2, dinv, hw2);

    // 5) layer-2 gather + bias -> z (fp32 out), XCD channel-sliced x2
    k_gather2<<<NN / 2, 256, 0, stream>>>(off, csr, dinv, hw2, b2, out_z);

    // 6) link prediction (16 lanes/edge, grid exact)
    k_linkpred<<<NEL * 16 / 256, 256, 0, stream>>>(lsrc, ldst, out_z, Wl, bl, out_pred);
}

// Round 16
// 308.151 us; speedup vs baseline: 1.4922x; 1.4922x over previous
//
#include <hip/hip_runtime.h>
#include <hip/hip_fp16.h>

#define NN 100000     // num nodes
#define NE 1600000    // num edges
#define NEL 200000    // link-pred edges
#define TM 64         // nodes per block in k_hw1
#define TM2 128       // nodes per block in k_hw2

// Bucketed CSR build (R12 config — best measured): bucket = dst >> 9.
#define NBUCK 196     // ceil(NN/512)
#define CAPB  10240   // per-bucket capacity (mean 8163, sigma ~90)
#define TPE   8192    // edges per k_part block (196 blocks)

// ---------------- CSR build, pass A: partition edges into buckets ----------
// LDS histogram per 8192-edge tile -> one global atomicAdd per (block,bucket)
// reserves space -> ranked writes (~42-entry contiguous runs; scattered fill
// measured 10-16x write amp in R4/R9/R11, this is ~1.2x).
__global__ __launch_bounds__(256) void k_part(const int* __restrict__ src,
                                              const int* __restrict__ dst,
                                              int* __restrict__ gcur,
                                              int* __restrict__ part) {
    __shared__ int hist[NBUCK];
    __shared__ int base[NBUCK];
    __shared__ int rk[NBUCK];
    int tid = threadIdx.x;
    for (int i = tid; i < NBUCK; i += 256) { hist[i] = 0; rk[i] = 0; }
    __syncthreads();
    int e0 = blockIdx.x * TPE;
    int e1 = min(e0 + TPE, NE);
    for (int e = e0 + tid; e < e1; e += 256)
        atomicAdd(&hist[dst[e] >> 9], 1);
    __syncthreads();
    for (int i = tid; i < NBUCK; i += 256)
        base[i] = i * CAPB + atomicAdd(&gcur[i], hist[i]);
    __syncthreads();
    for (int e = e0 + tid; e < e1; e += 256) {
        int d = dst[e];
        int s = src[e];
        int b = d >> 9;
        int r = atomicAdd(&rk[b], 1);
        part[base[b] + r] = ((d & 511) << 17) | s;   // src < 2^17
    }
}

// ---------------- CSR build, pass B: per-bucket LDS sort (prefix fused) ----
// One block per 512-dst bucket; inline 196-count prefix (no k_bscan2 launch).
// off[] end convention: row d = [off[d-1], off[d]), off[-1] = 0.
__global__ __launch_bounds__(256) void k_build(const int* __restrict__ gcur,
                                               const int* __restrict__ part,
                                               int* __restrict__ csr,
                                               int* __restrict__ off,
                                               float* __restrict__ dinv) {
    __shared__ int cnts[256];
    __shared__ int hist[512];
    __shared__ int loff[512];
    __shared__ int ssum[256];
    __shared__ int csrbuf[CAPB];
    int b = blockIdx.x;
    int tid = threadIdx.x;
    cnts[tid] = (tid < NBUCK) ? gcur[tid] : 0;       // inline bucket prefix
    __syncthreads();
    for (int st = 1; st < 256; st <<= 1) {
        int tmp = (tid >= st) ? cnts[tid - st] : 0;
        __syncthreads();
        cnts[tid] += tmp;
        __syncthreads();
    }
    int obase = (b == 0) ? 0 : cnts[b - 1];
    int cnt = gcur[b];
    int pbase = b * CAPB;
    hist[tid] = 0; hist[tid + 256] = 0;
    __syncthreads();
    for (int i = tid; i < cnt; i += 256)
        atomicAdd(&hist[part[pbase + i] >> 17], 1);
    __syncthreads();
    int a0 = hist[2 * tid], a1 = hist[2 * tid + 1];
    int pairs = a0 + a1;
    ssum[tid] = pairs;
    __syncthreads();
    for (int st = 1; st < 256; st <<= 1) {
        int tmp = (tid >= st) ? ssum[tid - st] : 0;
        __syncthreads();
        ssum[tid] += tmp;
        __syncthreads();
    }
    int pexcl = ssum[tid] - pairs;
    loff[2 * tid] = pexcl;
    loff[2 * tid + 1] = pexcl + a0;
    __syncthreads();
    for (int i = tid; i < 512; i += 256) {
        int d = b * 512 + i;
        if (d < NN) {
            int c = hist[i];
            off[d] = obase + loff[i] + c;            // end of row d
            dinv[d] = rsqrtf((float)(c + 1));        // +1 self-loop
        }
    }
    hist[tid] = 0; hist[tid + 256] = 0;              // reuse as rank counters
    __syncthreads();
    for (int i = tid; i < cnt; i += 256) {
        int rec = part[pbase + i];
        int dl = rec >> 17;
        int r = atomicAdd(&hist[dl], 1);
        csrbuf[loff[dl] + r] = rec & 0x1FFFF;
    }
    __syncthreads();
    for (int i = tid; i < cnt; i += 256)             // coalesced flush
        csr[obase + i] = csrbuf[i];
}

// ---------------- hw1' = dinv * ([x|pos] @ W1)  (80 -> 64), fp16 out -------
__global__ __launch_bounds__(256) void k_hw1(const float* __restrict__ x,
                                             const float* __restrict__ pos,
                                             const float* __restrict__ W1,
                                             const float* __restrict__ dinv,
                                             __half* __restrict__ hw1) {
    __shared__ float sh[TM * 80];
    __shared__ float sw[80 * 64];
    int tid = threadIdx.x;
    for (int t = tid; t < 80 * 64; t += 256) sw[t] = W1[t];
    int nb = blockIdx.x * TM;
    for (int i = tid; i < TM * 64; i += 256) {
        int node = i >> 6, ch = i & 63;
        int g = nb + node;
        sh[node * 80 + ch] = (g < NN) ? x[g * 64 + ch] : 0.0f;
    }
    for (int i = tid; i < TM * 16; i += 256) {
        int node = i >> 4, ch = i & 15;
        int g = nb + node;
        sh[node * 80 + 64 + ch] = (g < NN) ? pos[g * 16 + ch] : 0.0f;
    }
    __syncthreads();
    int j  = (tid & 15) * 4;
    int nl = (tid >> 4) * 4;
    float a00=0,a01=0,a02=0,a03=0, a10=0,a11=0,a12=0,a13=0;
    float a20=0,a21=0,a22=0,a23=0, a30=0,a31=0,a32=0,a33=0;
#pragma unroll 4
    for (int k = 0; k < 80; ++k) {
        float4 wv = *(const float4*)&sw[k * 64 + j];
        float h0 = sh[(nl + 0) * 80 + k];
        float h1 = sh[(nl + 1) * 80 + k];
        float h2 = sh[(nl + 2) * 80 + k];
        float h3 = sh[(nl + 3) * 80 + k];
        a00 += h0 * wv.x; a01 += h0 * wv.y; a02 += h0 * wv.z; a03 += h0 * wv.w;
        a10 += h1 * wv.x; a11 += h1 * wv.y; a12 += h1 * wv.z; a13 += h1 * wv.w;
        a20 += h2 * wv.x; a21 += h2 * wv.y; a22 += h2 * wv.z; a23 += h2 * wv.w;
        a30 += h3 * wv.x; a31 += h3 * wv.y; a32 += h3 * wv.z; a33 += h3 * wv.w;
    }
    int g0 = nb + nl;
    union { __half2 h2v[2]; float2 f2; } u;
#define STORE_ROW(r, b0, b1, b2, b3)                                          \
    if (g0 + r < NN) {                                                        \
        float sc = dinv[g0 + r];                                              \
        u.h2v[0] = __floats2half2_rn(b0 * sc, b1 * sc);                       \
        u.h2v[1] = __floats2half2_rn(b2 * sc, b3 * sc);                       \
        *(float2*)&hw1[(g0 + r) * 64 + j] = u.f2;                             \
    }
    STORE_ROW(0, a00, a01, a02, a03)
    STORE_ROW(1, a10, a11, a12, a13)
    STORE_ROW(2, a20, a21, a22, a23)
    STORE_ROW(3, a30, a31, a32, a33)
#undef STORE_ROW
}

// ---------------- layer-1 gather (R12 version: 54.4 us measured) -----------
// h2[d][c] = relu(b1[c] + dinv[d] * (sum_e hw1'[s] + hw1'[d]))
// Full 64-lane rows, shuffle-free edge loop, 8 outstanding 128B gathers.
// R15 channel-slicing regressed 3.2x (sector granularity) — do not re-slice.
__global__ __launch_bounds__(256) void k_gather1(const int* __restrict__ off,
                                                 const int* __restrict__ csr,
                                                 const float* __restrict__ dinv,
                                                 const __half* __restrict__ hw,
                                                 const float* __restrict__ b1,
                                                 __half* __restrict__ h2out) {
    int lane = threadIdx.x & 63;
    int wave = threadIdx.x >> 6;
    int d = blockIdx.x * 4 + wave;             // grid = NN/4 exactly
    int start = (d == 0) ? 0 : off[d - 1];
    int end = off[d];
    start = __builtin_amdgcn_readfirstlane(start);   // SGPR bounds ->
    end   = __builtin_amdgcn_readfirstlane(end);     // scalar csr loads
    float dd = dinv[d];
    float hself = __half2float(hw[d * 64 + lane]);   // hoisted
    float acc0 = 0.0f, acc1 = 0.0f, acc2 = 0.0f, acc3 = 0.0f;
    int e = start;
    for (; e + 7 < end; e += 8) {              // 8 outstanding gathers
        int s0 = csr[e],     s1 = csr[e + 1];
        int s2 = csr[e + 2], s3 = csr[e + 3];
        int s4 = csr[e + 4], s5 = csr[e + 5];
        int s6 = csr[e + 6], s7 = csr[e + 7];
        float g0 = __half2float(hw[s0 * 64 + lane]);
        float g1 = __half2float(hw[s1 * 64 + lane]);
        float g2 = __half2float(hw[s2 * 64 + lane]);
        float g3 = __half2float(hw[s3 * 64 + lane]);
        float g4 = __half2float(hw[s4 * 64 + lane]);
        float g5 = __half2float(hw[s5 * 64 + lane]);
        float g6 = __half2float(hw[s6 * 64 + lane]);
        float g7 = __half2float(hw[s7 * 64 + lane]);
        acc0 += g0; acc1 += g1; acc2 += g2; acc3 += g3;
        acc0 += g4; acc1 += g5; acc2 += g6; acc3 += g7;
    }
    for (; e < end; ++e)                       // uniform remainder
        acc0 += __half2float(hw[csr[e] * 64 + lane]);
    float v = fmaxf(b1[lane] + dd * (((acc0 + acc1) + (acc2 + acc3)) + hself), 0.0f);
    h2out[d * 64 + lane] = __float2half_rn(v);
}

// ---------------- hw2' = dinv * (h2 @ W2)  (64 -> 32), fp16 in/out ---------
__global__ __launch_bounds__(256) void k_hw2(const __half* __restrict__ h2,
                                             const float* __restrict__ W2,
                                             const float* __restrict__ dinv,
                                             __half* __restrict__ hw2) {
    __shared__ float sh[TM2 * 65];  // [node][feat], stride 65 (pad)
    __shared__ float sw[64 * 32];
    int tid = threadIdx.x;
    for (int t = tid; t < 64 * 32; t += 256) sw[t] = W2[t];
    int nb = blockIdx.x * TM2;
    for (int i = tid; i < TM2 * 64; i += 256) {
        int node = i >> 6, ch = i & 63;
        int g = nb + node;
        sh[node * 65 + ch] = (g < NN) ? __half2float(h2[g * 64 + ch]) : 0.0f;
    }
    __syncthreads();
    int j  = (tid & 7) * 4;
    int nl = (tid >> 3) * 4;
    float a00=0,a01=0,a02=0,a03=0, a10=0,a11=0,a12=0,a13=0;
    float a20=0,a21=0,a22=0,a23=0, a30=0,a31=0,a32=0,a33=0;
#pragma unroll 4
    for (int k = 0; k < 64; ++k) {
        float4 wv = *(const float4*)&sw[k * 32 + j];
        float h0 = sh[(nl + 0) * 65 + k];
        float h1 = sh[(nl + 1) * 65 + k];
        float h2v = sh[(nl + 2) * 65 + k];
        float h3 = sh[(nl + 3) * 65 + k];
        a00 += h0 * wv.x;  a01 += h0 * wv.y;  a02 += h0 * wv.z;  a03 += h0 * wv.w;
        a10 += h1 * wv.x;  a11 += h1 * wv.y;  a12 += h1 * wv.z;  a13 += h1 * wv.w;
        a20 += h2v * wv.x; a21 += h2v * wv.y; a22 += h2v * wv.z; a23 += h2v * wv.w;
        a30 += h3 * wv.x;  a31 += h3 * wv.y;  a32 += h3 * wv.z;  a33 += h3 * wv.w;
    }
    int g0 = nb + nl;
    union { __half2 h2v2[2]; float2 f2; } u;
#define STORE_ROW(r, b0, b1, b2, b3)                                          \
    if (g0 + r < NN) {                                                        \
        float sc = dinv[g0 + r];                                              \
        u.h2v2[0] = __floats2half2_rn(b0 * sc, b1 * sc);                      \
        u.h2v2[1] = __floats2half2_rn(b2 * sc, b3 * sc);                      \
        *(float2*)&hw2[(g0 + r) * 32 + j] = u.f2;                             \
    }
    STORE_ROW(0, a00, a01, a02, a03)
    STORE_ROW(1, a10, a11, a12, a13)
    STORE_ROW(2, a20, a21, a22, a23)
    STORE_ROW(3, a30, a31, a32, a33)
#undef STORE_ROW
}

// ---------------- layer-2 gather (R12 version) -----------------------------
// z[d][j] = b2[j] + dinv[d] * (sum_e hw2'[s] + hw2'[d])
__global__ __launch_bounds__(256) void k_gather2(const int* __restrict__ off,
                                                 const int* __restrict__ csr,
                                                 const float* __restrict__ dinv,
                                                 const __half* __restrict__ hw,
                                                 const float* __restrict__ b2,
                                                 float* __restrict__ outz) {
    int lane = threadIdx.x & 63;
    int half = lane >> 5;
    int j = lane & 31;
    int wave = threadIdx.x >> 6;
    int d = blockIdx.x * 4 + wave;             // grid = NN/4 exactly
    int start = (d == 0) ? 0 : off[d - 1];
    int end = off[d];
    start = __builtin_amdgcn_readfirstlane(start);
    end   = __builtin_amdgcn_readfirstlane(end);
    float dd = dinv[d];
    float hself = __half2float(hw[d * 32 + j]);      // hoisted
    float accA = 0.0f, accB = 0.0f, accC = 0.0f, accD = 0.0f;
    int e = start;
    for (; e + 7 < end; e += 8) {              // 4 gathers per half in flight
        int sA = csr[e + half];
        int sB = csr[e + half + 2];
        int sC = csr[e + half + 4];
        int sD = csr[e + half + 6];
        accA += __half2float(hw[sA * 32 + j]);
        accB += __half2float(hw[sB * 32 + j]);
        accC += __half2float(hw[sC * 32 + j]);
        accD += __half2float(hw[sD * 32 + j]);
    }
    for (int ee = e + half; ee < end; ee += 2)       // divergent-safe tail
        accA += __half2float(hw[csr[ee] * 32 + j]);
    float acc = (accA + accB) + (accC + accD);
    acc += __shfl(acc, lane ^ 32, 64);         // combine halves (full exec)
    if (half == 0)
        outz[d * 32 + j] = b2[j] + dd * (acc + hself);
}

// ---------------- link prediction head: 16 lanes per edge ------------------
__global__ __launch_bounds__(256) void k_linkpred(const int* __restrict__ sidx,
                                                  const int* __restrict__ didx,
                                                  const float* __restrict__ z,
                                                  const float* __restrict__ Wl,
                                                  const float* __restrict__ bl,
                                                  float* __restrict__ pred) {
    int t = blockIdx.x * blockDim.x + threadIdx.x;
    int e = t >> 4;
    int l = t & 15;
    int s = sidx[e], d = didx[e];
    float2 zs = *(const float2*)&z[s * 32 + 2 * l];
    float2 zd = *(const float2*)&z[d * 32 + 2 * l];
    float2 ws = *(const float2*)&Wl[2 * l];
    float2 wd = *(const float2*)&Wl[32 + 2 * l];
    float v = zs.x * ws.x + zs.y * ws.y + zd.x * wd.x + zd.y * wd.y;
    v += __shfl_xor(v, 1, 64);
    v += __shfl_xor(v, 2, 64);
    v += __shfl_xor(v, 4, 64);
    v += __shfl_xor(v, 8, 64);
    if (l == 0) pred[e] = v + bl[0];
}

extern "C" void kernel_launch(void* const* d_in, const int* in_sizes, int n_in,
                              void* d_out, int out_size, void* d_ws, size_t ws_size,
                              hipStream_t stream) {
    const float* x    = (const float*)d_in[0];
    const float* pos  = (const float*)d_in[1];
    const float* W1   = (const float*)d_in[2];
    const float* b1   = (const float*)d_in[3];
    const float* W2   = (const float*)d_in[4];
    const float* b2   = (const float*)d_in[5];
    const float* Wl   = (const float*)d_in[6];
    const float* bl   = (const float*)d_in[7];
    const int*   ei   = (const int*)d_in[8];   // [2, NE]
    const int*   eli  = (const int*)d_in[9];   // [2, NEL]
    const int* src  = ei;
    const int* dst  = ei + NE;
    const int* lsrc = eli;
    const int* ldst = eli + NEL;

    float* out_z    = (float*)d_out;            // [NN, 32]
    float* out_pred = (float*)d_out + NN * 32;  // [NEL]

    // workspace: dinv[NN]f | off[NN]i | gcur[NBUCK] | csr[NE]i |
    //            hw1'[NN*64]h (aliases part[NBUCK*CAPB]i = 8.0 MB, dead after
    //            k_build) | h2[NN*64]h | hw2'[NN*32]h   ~= 39.2 MB
    float*  dinv  = (float*)d_ws;
    int*    off   = (int*)(dinv + NN);
    int*    gcur  = off + NN;
    int*    csr   = gcur + NBUCK;
    __half* hw1   = (__half*)(csr + NE);
    int*    part  = (int*)hw1;                  // 8.0 MB <= hw1's 12.8 MB
    __half* h2    = hw1 + NN * 64;
    __half* hw2   = h2 + NN * 64;

    // 1) CSR build: partition -> per-bucket LDS sort (prefix fused, +dinv)
    hipMemsetAsync(gcur, 0, NBUCK * sizeof(int), stream);
    k_part<<<(NE + TPE - 1) / TPE, 256, 0, stream>>>(src, dst, gcur, part);
    k_build<<<NBUCK, 256, 0, stream>>>(gcur, part, csr, off, dinv);

    // 2) hw1' = dinv * ([x|pos] @ W1), fp16  (overwrites part — now dead)
    k_hw1<<<(NN + TM - 1) / TM, 256, 0, stream>>>(x, pos, W1, dinv, hw1);

    // 3) layer-1 gather + bias + relu -> h2 (fp16), full-wave rows
    k_gather1<<<NN / 4, 256, 0, stream>>>(off, csr, dinv, hw1, b1, h2);

    // 4) hw2' = dinv * (h2 @ W2), fp16
    k_hw2<<<(NN + TM2 - 1) / TM2, 256, 0, stream>>>(h2, W2, dinv, hw2);

    // 5) layer-2 gather + bias -> z (fp32 out)
    k_gather2<<<NN / 4, 256, 0, stream>>>(off, csr, dinv, hw2, b2, out_z);

    // 6) link prediction (16 lanes/edge, grid exact)
    k_linkpred<<<NEL * 16 / 256, 256, 0, stream>>>(lsrc, ldst, out_z, Wl, bl, out_pred);
}